// Round 5
// baseline (233.664 us; speedup 1.0000x reference)
//
#include <hip/hip_runtime.h>

#define PH 7
#define PW 7
#define SR 2
#define SY (PH * SR)   // 14
#define SX (PW * SR)   // 14
#define CH 256
#define FH 200
#define FW 272
#define BINS (PH * PW) // 49
#define NPIX (FH * FW) // 54400
#define MAXN 1024

typedef float  floatx4 __attribute__((ext_vector_type(4)));

__device__ __forceinline__ unsigned short f2bf(float f) {
    unsigned x = __float_as_uint(f);
    return (unsigned short)((x + 0x7fffu + ((x >> 16) & 1u)) >> 16);
}
__device__ __forceinline__ float bflo(unsigned u) { return __uint_as_float(u << 16); }
__device__ __forceinline__ float bfhi(unsigned u) { return __uint_as_float(u & 0xffff0000u); }

// ---------- Pass 0: ROI spatial sort -> XCD-chunked permutation ----------
// Counting sort by key = (batch, y-center bucket). Sorted position p maps
// bijectively to blockIdx bid = 8*j + xcd so same-XCD blocks process ROIs
// with adjacent y (L2 overlap). v2: single-wave shfl scan (4 barriers total
// vs 17 full-block barriers of the Hillis-Steele version).
__global__ __launch_bounds__(256) void sortperm_kernel(
    const float* __restrict__ rois, int* __restrict__ perm, int N) {
    const int t = threadIdx.x;
    if (N > MAXN) {                      // uniform branch: identity fallback
        for (int i = t; i < N; i += 256) perm[i] = i;
        return;
    }
    __shared__ unsigned short s_key[MAXN];
    __shared__ int s_base[256];
    __shared__ int s_cnt[256];
    if (t < 256) s_cnt[t] = 0;
    __syncthreads();
    for (int i = t; i < N; i += 256) {
        const float b  = rois[i * 5 + 0];
        const float yc = (rois[i * 5 + 2] + rois[i * 5 + 4]) * (0.5f * 0.25f);
        int yk = (int)(yc * (128.0f / 200.0f));
        yk = min(127, max(0, yk));
        const int key = (((int)b) & 1) * 128 + yk;
        s_key[i] = (unsigned short)key;
        atomicAdd(&s_cnt[key], 1);
    }
    __syncthreads();
    if (t < 64) {                        // wave 0: scan 256 bins, 4/lane
        const int h0 = s_cnt[t * 4], h1 = s_cnt[t * 4 + 1];
        const int h2 = s_cnt[t * 4 + 2], h3 = s_cnt[t * 4 + 3];
        const int sum = h0 + h1 + h2 + h3;
        int inc = sum;
        #pragma unroll
        for (int off = 1; off < 64; off <<= 1) {
            const int v = __shfl_up(inc, off, 64);
            if (t >= off) inc += v;
        }
        const int base = inc - sum;      // exclusive prefix
        s_base[t * 4]     = base;
        s_base[t * 4 + 1] = base + h0;
        s_base[t * 4 + 2] = base + h0 + h1;
        s_base[t * 4 + 3] = base + h0 + h1 + h2;
    }
    __syncthreads();
    if (t < 256) s_cnt[t] = 0;           // reuse as running offsets
    __syncthreads();
    for (int i = t; i < N; i += 256) {
        const int k = s_key[i];
        const int p = s_base[k] + atomicAdd(&s_cnt[k], 1);   // sorted position
        const int q = N >> 3, r = N & 7; // bijective chunked XCD transform
        int xcd, j;
        if (p < r * (q + 1)) { xcd = p / (q + 1); j = p - xcd * (q + 1); }
        else { const int pp = p - r * (q + 1); xcd = r + pp / q; j = pp - (xcd - r) * q; }
        perm[8 * j + xcd] = i;
    }
}

// ---------- Pass 1: feat [B,C,H,W] fp32 -> featT [B,H,W,C] bf16 ----------
__global__ __launch_bounds__(256) void transpose_kernel(
    const float* __restrict__ feat, unsigned short* __restrict__ featT) {
    __shared__ __align__(16) unsigned short tile[FW][66];   // 35904 B
    const int t  = threadIdx.x;
    const int bh = blockIdx.x;                // b*FH + h
    const int c0 = blockIdx.y * 64;
    const int b  = bh / FH;
    const int h  = bh % FH;

    // Load: 4 lanes per channel row, 17 float4 each (68 float4 = 272 w)
    const int cl  = t >> 2;                   // 0..63
    const int wq0 = t & 3;
    const floatx4* __restrict__ src = (const floatx4*)(
        feat + (size_t)b * CH * NPIX + (size_t)(c0 + cl) * NPIX + (size_t)h * FW);
    #pragma unroll
    for (int k = 0; k < 17; ++k) {
        const int fidx = wq0 + 4 * k;         // 0..67
        const floatx4 v = __builtin_nontemporal_load(src + fidx);
        const int w = fidx * 4;
        tile[w + 0][cl] = f2bf(v.x);
        tile[w + 1][cl] = f2bf(v.y);
        tile[w + 2][cl] = f2bf(v.z);
        tile[w + 3][cl] = f2bf(v.w);
    }
    __syncthreads();

    // Store: per w, 64 bf16 = 32 dwords = 128 B aligned chunk (full L2 line)
    const int cd = t & 31;                    // c-pair
    const int wl = t >> 5;                    // 0..7
    unsigned* __restrict__ dstu = (unsigned*)featT;
    const size_t pixbase = (size_t)bh * FW;
    #pragma unroll
    for (int k = 0; k < 34; ++k) {
        const int w = wl + 8 * k;             // 272 = 8*34
        const unsigned p = *(const unsigned*)&tile[w][2 * cd];
        dstu[(pixbase + w) * (CH / 2) + (c0 >> 1) + cd] = p;
    }
}

// ---------- Pass 2: ROIAlign on channels-last bf16 featT ----------
__global__ __launch_bounds__(512) void roialign_cl_kernel(
    const unsigned short* __restrict__ featT,
    const float* __restrict__ rois,
    const int* __restrict__ perm,
    float* __restrict__ out, int N) {
    __shared__ int   s_yl[SY], s_yh[SY];          // offsets in DWORDS
    __shared__ float s_ly[SY], s_hy[SY];          // 0.5*weight, validity folded
    __shared__ int   s_xl[SX], s_xh[SX];
    __shared__ float s_lx[SX], s_hx[SX];
    __shared__ __align__(16) unsigned short s_out16[BINS * CH]; // 25088 B, [bin][c]

    const int n   = perm[blockIdx.x];             // XCD-locality permutation
    const int tid = threadIdx.x;
    const float* __restrict__ roi = rois + (size_t)n * 5;

    if (tid < SY + SX) {
        const bool isy = (tid < SY);
        const int  idx = isy ? tid : tid - SY;
        const int  lim = isy ? FH : FW;
        const float start = (isy ? roi[2] : roi[1]) * 0.25f;
        const float end_  = (isy ? roi[4] : roi[3]) * 0.25f;
        const float len   = fmaxf(end_ - start, 1.0f);
        const float binsz = len * (isy ? (1.0f / PH) : (1.0f / PW));
        const float s = start + ((float)idx + 0.5f) * (1.0f / SR) * binsz;
        const float valid = (s > -1.0f && s < (float)lim) ? 0.5f : 0.0f; // fold 1/SR avg
        const float cc = fminf(fmaxf(s, 0.0f), (float)(lim - 1));
        const int   lo = (int)floorf(cc);
        const int   hi = min(lo + 1, lim - 1);
        const float l  = (cc - (float)lo) * valid;
        const float hw = (1.0f - (cc - (float)lo)) * valid;
        const int   rowstride = FW * (CH / 2);     // dwords per y
        if (isy) { s_yl[idx] = lo * rowstride; s_yh[idx] = hi * rowstride;
                   s_ly[idx] = l; s_hy[idx] = hw; }
        else     { s_xl[idx] = lo * (CH / 2);  s_xh[idx] = hi * (CH / 2);
                   s_lx[idx] = l; s_hx[idx] = hw; }
    }
    __syncthreads();

    const int b  = (int)roi[0];
    const int c8 = tid & 31;              // channel octet: channels 8*c8 .. 8*c8+7
    const int g  = tid >> 5;              // 16 bin groups
    const unsigned* __restrict__ fbu =
        (const unsigned*)featT + (size_t)b * (FH * FW * (CH / 2)) + c8 * 4;

    const int bstart = g * 3;
    const int bend   = (g == 15) ? BINS : bstart + 3;  // groups: 15x3 + 1x4

    // unroll 2: let the compiler issue bin k+1's gathers under bin k's math
    #pragma unroll 2
    for (int bin = bstart; bin < bend; ++bin) {
        const int ph = bin / 7;
        const int pw = bin - ph * 7;
        const int sy = ph * SR, sx = pw * SR;
        float a0 = 0.f, a1 = 0.f, a2 = 0.f, a3 = 0.f;
        float a4 = 0.f, a5 = 0.f, a6 = 0.f, a7 = 0.f;
        #pragma unroll
        for (int i = 0; i < SR; ++i) {
            const int   yo0 = s_yl[sy + i], yo1 = s_yh[sy + i];
            const float wy1 = s_ly[sy + i], wy0 = s_hy[sy + i];
            #pragma unroll
            for (int j = 0; j < SR; ++j) {
                const int   xo0 = s_xl[sx + j], xo1 = s_xh[sx + j];
                const float wx1 = s_lx[sx + j], wx0 = s_hx[sx + j];
                const uint4 u00 = *(const uint4*)(fbu + yo0 + xo0);
                const uint4 u01 = *(const uint4*)(fbu + yo0 + xo1);
                const uint4 u10 = *(const uint4*)(fbu + yo1 + xo0);
                const uint4 u11 = *(const uint4*)(fbu + yo1 + xo1);
                const float w00 = wy0 * wx0, w01 = wy0 * wx1;
                const float w10 = wy1 * wx0, w11 = wy1 * wx1;
                a0 += w00 * bflo(u00.x) + w01 * bflo(u01.x) + w10 * bflo(u10.x) + w11 * bflo(u11.x);
                a1 += w00 * bfhi(u00.x) + w01 * bfhi(u01.x) + w10 * bfhi(u10.x) + w11 * bfhi(u11.x);
                a2 += w00 * bflo(u00.y) + w01 * bflo(u01.y) + w10 * bflo(u10.y) + w11 * bflo(u11.y);
                a3 += w00 * bfhi(u00.y) + w01 * bfhi(u01.y) + w10 * bfhi(u10.y) + w11 * bfhi(u11.y);
                a4 += w00 * bflo(u00.z) + w01 * bflo(u01.z) + w10 * bflo(u10.z) + w11 * bflo(u11.z);
                a5 += w00 * bfhi(u00.z) + w01 * bfhi(u01.z) + w10 * bfhi(u10.z) + w11 * bfhi(u11.z);
                a6 += w00 * bflo(u00.w) + w01 * bflo(u01.w) + w10 * bflo(u10.w) + w11 * bflo(u11.w);
                a7 += w00 * bfhi(u00.w) + w01 * bfhi(u01.w) + w10 * bfhi(u10.w) + w11 * bfhi(u11.w);
            }
        }
        uint4 p;
        p.x = (unsigned)f2bf(a0) | ((unsigned)f2bf(a1) << 16);
        p.y = (unsigned)f2bf(a2) | ((unsigned)f2bf(a3) << 16);
        p.z = (unsigned)f2bf(a4) | ((unsigned)f2bf(a5) << 16);
        p.w = (unsigned)f2bf(a6) | ((unsigned)f2bf(a7) << 16);
        const int col = (c8 ^ (bin & 31)) * 8;     // per-bin octet swizzle
        *(uint4*)&s_out16[bin * CH + col] = p;
    }
    __syncthreads();

    // Coalesced fp32 non-temporal flush of this ROI's [C, 7, 7] tile
    float* __restrict__ outn = out + (size_t)n * (CH * BINS);
    #pragma unroll 1
    for (int k = 0; k < 24; ++k) {                 // 24*512 = 12288
        const int e   = k * 512 + tid;             // = c*49 + bin
        const int c   = e / 49;
        const int bin = e - c * 49;
        const int oct = (c >> 3) ^ (bin & 31);     // undo swizzle
        __builtin_nontemporal_store(
            bflo((unsigned)s_out16[bin * CH + oct * 8 + (c & 7)]), &outn[e]);
    }
    if (tid < 256) {                               // tail: 12288..12543
        const int e   = 12288 + tid;
        const int c   = e / 49;
        const int bin = e - c * 49;
        const int oct = (c >> 3) ^ (bin & 31);
        __builtin_nontemporal_store(
            bflo((unsigned)s_out16[bin * CH + oct * 8 + (c & 7)]), &outn[e]);
    }
}

// ---------- Fallback (fp32, no workspace) ----------
__global__ __launch_bounds__(256) void roialign_kernel(
    const float* __restrict__ feat,
    const float* __restrict__ rois,
    float* __restrict__ out, int N) {
    __shared__ int   s_yl[SY], s_yh[SY];
    __shared__ float s_ly[SY], s_hy[SY];
    __shared__ int   s_xl[SX], s_xh[SX];
    __shared__ float s_lx[SX], s_hx[SX];
    __shared__ float s_out[CH * BINS];

    const int n   = blockIdx.x;
    const int tid = threadIdx.x;
    const float* __restrict__ roi = rois + (size_t)n * 5;

    if (tid < SY + SX) {
        const bool isy = (tid < SY);
        const int  idx = isy ? tid : tid - SY;
        const int  lim = isy ? FH : FW;
        const float start = (isy ? roi[2] : roi[1]) * 0.25f;
        const float end_  = (isy ? roi[4] : roi[3]) * 0.25f;
        const float len   = fmaxf(end_ - start, 1.0f);
        const float binsz = len * (isy ? (1.0f / PH) : (1.0f / PW));
        const float s = start + ((float)idx + 0.5f) * (1.0f / SR) * binsz;
        const float valid = (s > -1.0f && s < (float)lim) ? 1.0f : 0.0f;
        const float cc = fminf(fmaxf(s, 0.0f), (float)(lim - 1));
        const int   lo = (int)floorf(cc);
        const int   hi = min(lo + 1, lim - 1);
        const float l  = (cc - (float)lo) * valid;
        const float hw = (1.0f - (cc - (float)lo)) * valid;
        if (isy) { s_yl[idx] = lo; s_yh[idx] = hi; s_ly[idx] = l; s_hy[idx] = hw; }
        else     { s_xl[idx] = lo; s_xh[idx] = hi; s_lx[idx] = l; s_hx[idx] = hw; }
    }
    __syncthreads();

    const int b = (int)roi[0];
    const int c = tid;
    const float* __restrict__ fp = feat + ((size_t)b * CH + c) * (size_t)NPIX;

    #pragma unroll 1
    for (int ph = 0; ph < PH; ++ph) {
        const int sy0 = ph * SR;
        const float* r00 = fp + s_yl[sy0] * FW;
        const float* r01 = fp + s_yh[sy0] * FW;
        const float* r10 = fp + s_yl[sy0 + 1] * FW;
        const float* r11 = fp + s_yh[sy0 + 1] * FW;
        const float ly0 = s_ly[sy0],     hy0 = s_hy[sy0];
        const float ly1 = s_ly[sy0 + 1], hy1 = s_hy[sy0 + 1];
        for (int pw = 0; pw < PW; ++pw) {
            const int sx0 = pw * SR;
            float acc = 0.0f;
            #pragma unroll
            for (int j = 0; j < SR; ++j) {
                const int   xl = s_xl[sx0 + j], xh = s_xh[sx0 + j];
                const float lx = s_lx[sx0 + j], hx = s_hx[sx0 + j];
                acc += hy0 * (hx * r00[xl] + lx * r00[xh])
                     + ly0 * (hx * r01[xl] + lx * r01[xh]);
                acc += hy1 * (hx * r10[xl] + lx * r10[xh])
                     + ly1 * (hx * r11[xl] + lx * r11[xh]);
            }
            s_out[c * BINS + ph * PW + pw] = acc * 0.25f;
        }
    }
    __syncthreads();

    float* __restrict__ outn = out + (size_t)n * (CH * BINS);
    #pragma unroll
    for (int k = 0; k < BINS; ++k) {
        const int idx = k * 256 + tid;
        outn[idx] = s_out[idx];
    }
}

extern "C" void kernel_launch(void* const* d_in, const int* in_sizes, int n_in,
                              void* d_out, int out_size, void* d_ws, size_t ws_size,
                              hipStream_t stream) {
    const float* feat = (const float*)d_in[0];
    const float* rois = (const float*)d_in[1];
    float* out = (float*)d_out;
    const int N = in_sizes[1] / 5;
    const int B = in_sizes[0] / (CH * NPIX);
    const size_t featT_bytes = (size_t)B * CH * NPIX * sizeof(unsigned short);
    const size_t need = featT_bytes + (size_t)N * sizeof(int);

    if (ws_size >= need) {
        unsigned short* featT = (unsigned short*)d_ws;
        int* perm = (int*)((char*)d_ws + featT_bytes);
        sortperm_kernel<<<1, 256, 0, stream>>>(rois, perm, N);
        dim3 tgrid(B * FH, CH / 64);
        transpose_kernel<<<tgrid, 256, 0, stream>>>(feat, featT);
        roialign_cl_kernel<<<N, 512, 0, stream>>>(featT, rois, perm, out, N);
    } else {
        roialign_kernel<<<N, 256, 0, stream>>>(feat, rois, out, N);
    }
}

// Round 6
// 218.600 us; speedup vs baseline: 1.0689x; 1.0689x over previous
//
#include <hip/hip_runtime.h>

#define PH 7
#define PW 7
#define SR 2
#define SY (PH * SR)   // 14
#define SX (PW * SR)   // 14
#define CH 256
#define FH 200
#define FW 272
#define BINS (PH * PW) // 49
#define NPIX (FH * FW) // 54400
#define MAXN 1024

typedef float  floatx4 __attribute__((ext_vector_type(4)));

__device__ __forceinline__ unsigned short f2bf(float f) {
    unsigned x = __float_as_uint(f);
    return (unsigned short)((x + 0x7fffu + ((x >> 16) & 1u)) >> 16);
}
__device__ __forceinline__ float bflo(unsigned u) { return __uint_as_float(u << 16); }
__device__ __forceinline__ float bfhi(unsigned u) { return __uint_as_float(u & 0xffff0000u); }

// ---------- Pass 0: ROI spatial sort -> XCD-chunked permutation ----------
// Counting sort by key = (batch, y-center bucket). Sorted position p maps
// bijectively to blockIdx bid = 8*j + xcd so same-XCD blocks process ROIs
// with adjacent y (L2 overlap). Single-wave shfl scan, 4 barriers total.
__global__ __launch_bounds__(256) void sortperm_kernel(
    const float* __restrict__ rois, int* __restrict__ perm, int N) {
    const int t = threadIdx.x;
    if (N > MAXN) {                      // uniform branch: identity fallback
        for (int i = t; i < N; i += 256) perm[i] = i;
        return;
    }
    __shared__ unsigned short s_key[MAXN];
    __shared__ int s_base[256];
    __shared__ int s_cnt[256];
    if (t < 256) s_cnt[t] = 0;
    __syncthreads();
    for (int i = t; i < N; i += 256) {
        const float b  = rois[i * 5 + 0];
        const float yc = (rois[i * 5 + 2] + rois[i * 5 + 4]) * (0.5f * 0.25f);
        int yk = (int)(yc * (128.0f / 200.0f));
        yk = min(127, max(0, yk));
        const int key = (((int)b) & 1) * 128 + yk;
        s_key[i] = (unsigned short)key;
        atomicAdd(&s_cnt[key], 1);
    }
    __syncthreads();
    if (t < 64) {                        // wave 0: scan 256 bins, 4/lane
        const int h0 = s_cnt[t * 4], h1 = s_cnt[t * 4 + 1];
        const int h2 = s_cnt[t * 4 + 2], h3 = s_cnt[t * 4 + 3];
        const int sum = h0 + h1 + h2 + h3;
        int inc = sum;
        #pragma unroll
        for (int off = 1; off < 64; off <<= 1) {
            const int v = __shfl_up(inc, off, 64);
            if (t >= off) inc += v;
        }
        const int base = inc - sum;      // exclusive prefix
        s_base[t * 4]     = base;
        s_base[t * 4 + 1] = base + h0;
        s_base[t * 4 + 2] = base + h0 + h1;
        s_base[t * 4 + 3] = base + h0 + h1 + h2;
    }
    __syncthreads();
    if (t < 256) s_cnt[t] = 0;           // reuse as running offsets
    __syncthreads();
    for (int i = t; i < N; i += 256) {
        const int k = s_key[i];
        const int p = s_base[k] + atomicAdd(&s_cnt[k], 1);   // sorted position
        const int q = N >> 3, r = N & 7; // bijective chunked XCD transform
        int xcd, j;
        if (p < r * (q + 1)) { xcd = p / (q + 1); j = p - xcd * (q + 1); }
        else { const int pp = p - r * (q + 1); xcd = r + pp / q; j = pp - (xcd - r) * q; }
        perm[8 * j + xcd] = i;
    }
}

// ---------- Pass 1: feat [B,C,H,W] fp32 -> featT [B,H,W,C] bf16 ----------
__global__ __launch_bounds__(256) void transpose_kernel(
    const float* __restrict__ feat, unsigned short* __restrict__ featT) {
    __shared__ __align__(16) unsigned short tile[FW][66];   // 35904 B
    const int t  = threadIdx.x;
    const int bh = blockIdx.x;                // b*FH + h
    const int c0 = blockIdx.y * 64;
    const int b  = bh / FH;
    const int h  = bh % FH;

    // Load: 4 lanes per channel row, 17 float4 each (68 float4 = 272 w)
    const int cl  = t >> 2;                   // 0..63
    const int wq0 = t & 3;
    const floatx4* __restrict__ src = (const floatx4*)(
        feat + (size_t)b * CH * NPIX + (size_t)(c0 + cl) * NPIX + (size_t)h * FW);
    #pragma unroll
    for (int k = 0; k < 17; ++k) {
        const int fidx = wq0 + 4 * k;         // 0..67
        const floatx4 v = __builtin_nontemporal_load(src + fidx);
        const int w = fidx * 4;
        tile[w + 0][cl] = f2bf(v.x);
        tile[w + 1][cl] = f2bf(v.y);
        tile[w + 2][cl] = f2bf(v.z);
        tile[w + 3][cl] = f2bf(v.w);
    }
    __syncthreads();

    // Store: per w, 64 bf16 = 32 dwords = 128 B aligned chunk (full L2 line)
    const int cd = t & 31;                    // c-pair
    const int wl = t >> 5;                    // 0..7
    unsigned* __restrict__ dstu = (unsigned*)featT;
    const size_t pixbase = (size_t)bh * FW;
    #pragma unroll
    for (int k = 0; k < 34; ++k) {
        const int w = wl + 8 * k;             // 272 = 8*34
        const unsigned p = *(const unsigned*)&tile[w][2 * cd];
        dstu[(pixbase + w) * (CH / 2) + (c0 >> 1) + cd] = p;
    }
}

// ---------- Pass 2: ROIAlign on channels-last bf16 featT ----------
// unroll 1 is deliberate: unroll 2 doubles live uint4 load destinations,
// crosses a VGPR threshold at 512 threads/block and halves occupancy
// (measured +18 us regression, Round 5). TLP > ILP for this gather loop.
__global__ __launch_bounds__(512) void roialign_cl_kernel(
    const unsigned short* __restrict__ featT,
    const float* __restrict__ rois,
    const int* __restrict__ perm,
    float* __restrict__ out, int N) {
    __shared__ int   s_yl[SY], s_yh[SY];          // offsets in DWORDS
    __shared__ float s_ly[SY], s_hy[SY];          // 0.5*weight, validity folded
    __shared__ int   s_xl[SX], s_xh[SX];
    __shared__ float s_lx[SX], s_hx[SX];
    __shared__ __align__(16) unsigned short s_out16[BINS * CH]; // 25088 B, [bin][c]

    const int n   = perm[blockIdx.x];             // XCD-locality permutation
    const int tid = threadIdx.x;
    const float* __restrict__ roi = rois + (size_t)n * 5;

    if (tid < SY + SX) {
        const bool isy = (tid < SY);
        const int  idx = isy ? tid : tid - SY;
        const int  lim = isy ? FH : FW;
        const float start = (isy ? roi[2] : roi[1]) * 0.25f;
        const float end_  = (isy ? roi[4] : roi[3]) * 0.25f;
        const float len   = fmaxf(end_ - start, 1.0f);
        const float binsz = len * (isy ? (1.0f / PH) : (1.0f / PW));
        const float s = start + ((float)idx + 0.5f) * (1.0f / SR) * binsz;
        const float valid = (s > -1.0f && s < (float)lim) ? 0.5f : 0.0f; // fold 1/SR avg
        const float cc = fminf(fmaxf(s, 0.0f), (float)(lim - 1));
        const int   lo = (int)floorf(cc);
        const int   hi = min(lo + 1, lim - 1);
        const float l  = (cc - (float)lo) * valid;
        const float hw = (1.0f - (cc - (float)lo)) * valid;
        const int   rowstride = FW * (CH / 2);     // dwords per y
        if (isy) { s_yl[idx] = lo * rowstride; s_yh[idx] = hi * rowstride;
                   s_ly[idx] = l; s_hy[idx] = hw; }
        else     { s_xl[idx] = lo * (CH / 2);  s_xh[idx] = hi * (CH / 2);
                   s_lx[idx] = l; s_hx[idx] = hw; }
    }
    __syncthreads();

    const int b  = (int)roi[0];
    const int c8 = tid & 31;              // channel octet: channels 8*c8 .. 8*c8+7
    const int g  = tid >> 5;              // 16 bin groups
    const unsigned* __restrict__ fbu =
        (const unsigned*)featT + (size_t)b * (FH * FW * (CH / 2)) + c8 * 4;

    const int bstart = g * 3;
    const int bend   = (g == 15) ? BINS : bstart + 3;  // groups: 15x3 + 1x4

    #pragma unroll 1
    for (int bin = bstart; bin < bend; ++bin) {
        const int ph = bin / 7;
        const int pw = bin - ph * 7;
        const int sy = ph * SR, sx = pw * SR;
        float a0 = 0.f, a1 = 0.f, a2 = 0.f, a3 = 0.f;
        float a4 = 0.f, a5 = 0.f, a6 = 0.f, a7 = 0.f;
        #pragma unroll
        for (int i = 0; i < SR; ++i) {
            const int   yo0 = s_yl[sy + i], yo1 = s_yh[sy + i];
            const float wy1 = s_ly[sy + i], wy0 = s_hy[sy + i];
            #pragma unroll
            for (int j = 0; j < SR; ++j) {
                const int   xo0 = s_xl[sx + j], xo1 = s_xh[sx + j];
                const float wx1 = s_lx[sx + j], wx0 = s_hx[sx + j];
                const uint4 u00 = *(const uint4*)(fbu + yo0 + xo0);
                const uint4 u01 = *(const uint4*)(fbu + yo0 + xo1);
                const uint4 u10 = *(const uint4*)(fbu + yo1 + xo0);
                const uint4 u11 = *(const uint4*)(fbu + yo1 + xo1);
                const float w00 = wy0 * wx0, w01 = wy0 * wx1;
                const float w10 = wy1 * wx0, w11 = wy1 * wx1;
                a0 += w00 * bflo(u00.x) + w01 * bflo(u01.x) + w10 * bflo(u10.x) + w11 * bflo(u11.x);
                a1 += w00 * bfhi(u00.x) + w01 * bfhi(u01.x) + w10 * bfhi(u10.x) + w11 * bfhi(u11.x);
                a2 += w00 * bflo(u00.y) + w01 * bflo(u01.y) + w10 * bflo(u10.y) + w11 * bflo(u11.y);
                a3 += w00 * bfhi(u00.y) + w01 * bfhi(u01.y) + w10 * bfhi(u10.y) + w11 * bfhi(u11.y);
                a4 += w00 * bflo(u00.z) + w01 * bflo(u01.z) + w10 * bflo(u10.z) + w11 * bflo(u11.z);
                a5 += w00 * bfhi(u00.z) + w01 * bfhi(u01.z) + w10 * bfhi(u10.z) + w11 * bfhi(u11.z);
                a6 += w00 * bflo(u00.w) + w01 * bflo(u01.w) + w10 * bflo(u10.w) + w11 * bflo(u11.w);
                a7 += w00 * bfhi(u00.w) + w01 * bfhi(u01.w) + w10 * bfhi(u10.w) + w11 * bfhi(u11.w);
            }
        }
        uint4 p;
        p.x = (unsigned)f2bf(a0) | ((unsigned)f2bf(a1) << 16);
        p.y = (unsigned)f2bf(a2) | ((unsigned)f2bf(a3) << 16);
        p.z = (unsigned)f2bf(a4) | ((unsigned)f2bf(a5) << 16);
        p.w = (unsigned)f2bf(a6) | ((unsigned)f2bf(a7) << 16);
        const int col = (c8 ^ (bin & 31)) * 8;     // per-bin octet swizzle
        *(uint4*)&s_out16[bin * CH + col] = p;
    }
    __syncthreads();

    // Coalesced fp32 non-temporal flush of this ROI's [C, 7, 7] tile
    float* __restrict__ outn = out + (size_t)n * (CH * BINS);
    #pragma unroll 1
    for (int k = 0; k < 24; ++k) {                 // 24*512 = 12288
        const int e   = k * 512 + tid;             // = c*49 + bin
        const int c   = e / 49;
        const int bin = e - c * 49;
        const int oct = (c >> 3) ^ (bin & 31);     // undo swizzle
        __builtin_nontemporal_store(
            bflo((unsigned)s_out16[bin * CH + oct * 8 + (c & 7)]), &outn[e]);
    }
    if (tid < 256) {                               // tail: 12288..12543
        const int e   = 12288 + tid;
        const int c   = e / 49;
        const int bin = e - c * 49;
        const int oct = (c >> 3) ^ (bin & 31);
        __builtin_nontemporal_store(
            bflo((unsigned)s_out16[bin * CH + oct * 8 + (c & 7)]), &outn[e]);
    }
}

// ---------- Fallback (fp32, no workspace) ----------
__global__ __launch_bounds__(256) void roialign_kernel(
    const float* __restrict__ feat,
    const float* __restrict__ rois,
    float* __restrict__ out, int N) {
    __shared__ int   s_yl[SY], s_yh[SY];
    __shared__ float s_ly[SY], s_hy[SY];
    __shared__ int   s_xl[SX], s_xh[SX];
    __shared__ float s_lx[SX], s_hx[SX];
    __shared__ float s_out[CH * BINS];

    const int n   = blockIdx.x;
    const int tid = threadIdx.x;
    const float* __restrict__ roi = rois + (size_t)n * 5;

    if (tid < SY + SX) {
        const bool isy = (tid < SY);
        const int  idx = isy ? tid : tid - SY;
        const int  lim = isy ? FH : FW;
        const float start = (isy ? roi[2] : roi[1]) * 0.25f;
        const float end_  = (isy ? roi[4] : roi[3]) * 0.25f;
        const float len   = fmaxf(end_ - start, 1.0f);
        const float binsz = len * (isy ? (1.0f / PH) : (1.0f / PW));
        const float s = start + ((float)idx + 0.5f) * (1.0f / SR) * binsz;
        const float valid = (s > -1.0f && s < (float)lim) ? 1.0f : 0.0f;
        const float cc = fminf(fmaxf(s, 0.0f), (float)(lim - 1));
        const int   lo = (int)floorf(cc);
        const int   hi = min(lo + 1, lim - 1);
        const float l  = (cc - (float)lo) * valid;
        const float hw = (1.0f - (cc - (float)lo)) * valid;
        if (isy) { s_yl[idx] = lo; s_yh[idx] = hi; s_ly[idx] = l; s_hy[idx] = hw; }
        else     { s_xl[idx] = lo; s_xh[idx] = hi; s_lx[idx] = l; s_hx[idx] = hw; }
    }
    __syncthreads();

    const int b = (int)roi[0];
    const int c = tid;
    const float* __restrict__ fp = feat + ((size_t)b * CH + c) * (size_t)NPIX;

    #pragma unroll 1
    for (int ph = 0; ph < PH; ++ph) {
        const int sy0 = ph * SR;
        const float* r00 = fp + s_yl[sy0] * FW;
        const float* r01 = fp + s_yh[sy0] * FW;
        const float* r10 = fp + s_yl[sy0 + 1] * FW;
        const float* r11 = fp + s_yh[sy0 + 1] * FW;
        const float ly0 = s_ly[sy0],     hy0 = s_hy[sy0];
        const float ly1 = s_ly[sy0 + 1], hy1 = s_hy[sy0 + 1];
        for (int pw = 0; pw < PW; ++pw) {
            const int sx0 = pw * SR;
            float acc = 0.0f;
            #pragma unroll
            for (int j = 0; j < SR; ++j) {
                const int   xl = s_xl[sx0 + j], xh = s_xh[sx0 + j];
                const float lx = s_lx[sx0 + j], hx = s_hx[sx0 + j];
                acc += hy0 * (hx * r00[xl] + lx * r00[xh])
                     + ly0 * (hx * r01[xl] + lx * r01[xh]);
                acc += hy1 * (hx * r10[xl] + lx * r10[xh])
                     + ly1 * (hx * r11[xl] + lx * r11[xh]);
            }
            s_out[c * BINS + ph * PW + pw] = acc * 0.25f;
        }
    }
    __syncthreads();

    float* __restrict__ outn = out + (size_t)n * (CH * BINS);
    #pragma unroll
    for (int k = 0; k < BINS; ++k) {
        const int idx = k * 256 + tid;
        outn[idx] = s_out[idx];
    }
}

extern "C" void kernel_launch(void* const* d_in, const int* in_sizes, int n_in,
                              void* d_out, int out_size, void* d_ws, size_t ws_size,
                              hipStream_t stream) {
    const float* feat = (const float*)d_in[0];
    const float* rois = (const float*)d_in[1];
    float* out = (float*)d_out;
    const int N = in_sizes[1] / 5;
    const int B = in_sizes[0] / (CH * NPIX);
    const size_t featT_bytes = (size_t)B * CH * NPIX * sizeof(unsigned short);
    const size_t need = featT_bytes + (size_t)N * sizeof(int);

    if (ws_size >= need) {
        unsigned short* featT = (unsigned short*)d_ws;
        int* perm = (int*)((char*)d_ws + featT_bytes);
        sortperm_kernel<<<1, 256, 0, stream>>>(rois, perm, N);
        dim3 tgrid(B * FH, CH / 64);
        transpose_kernel<<<tgrid, 256, 0, stream>>>(feat, featT);
        roialign_cl_kernel<<<N, 512, 0, stream>>>(featT, rois, perm, out, N);
    } else {
        roialign_kernel<<<N, 256, 0, stream>>>(feat, rois, out, N);
    }
}

// Round 7
// 211.207 us; speedup vs baseline: 1.1063x; 1.0350x over previous
//
#include <hip/hip_runtime.h>

#define PH 7
#define PW 7
#define SR 2
#define SY (PH * SR)   // 14
#define SX (PW * SR)   // 14
#define CH 256
#define FH 200
#define FW 272
#define BINS (PH * PW) // 49
#define NPIX (FH * FW) // 54400
#define MAXN 1024

typedef float  floatx4 __attribute__((ext_vector_type(4)));

__device__ __forceinline__ unsigned short f2bf(float f) {
    unsigned x = __float_as_uint(f);
    return (unsigned short)((x + 0x7fffu + ((x >> 16) & 1u)) >> 16);
}
__device__ __forceinline__ float bflo(unsigned u) { return __uint_as_float(u << 16); }
__device__ __forceinline__ float bfhi(unsigned u) { return __uint_as_float(u & 0xffff0000u); }

// ---------- Pass 1 (+0): feat [B,C,H,W] fp32 -> featT [B,H,W,C] bf16,
// with the ROI sort fused into block (0,0) (saves one dispatch; the sort's
// ~1.5 us hides under the other 1599 BW-bound blocks). Sorted position p maps
// bijectively to blockIdx bid = 8*j + xcd so same-XCD roialign blocks process
// ROIs with adjacent y (L2 overlap).
__global__ __launch_bounds__(256) void transpose_kernel(
    const float* __restrict__ feat, unsigned short* __restrict__ featT,
    const float* __restrict__ rois, int* __restrict__ perm, int N) {
    __shared__ __align__(16) unsigned short tile[FW][66];   // 35904 B
    __shared__ unsigned short s_key[MAXN];                  // sort scratch (blk 0)
    __shared__ int s_base[256];
    __shared__ int s_cnt[256];
    const int t  = threadIdx.x;
    const int bh = blockIdx.x;                // b*FH + h
    const int c0 = blockIdx.y * 64;
    const int b  = bh / FH;
    const int h  = bh % FH;

    // Load: 4 lanes per channel row, 17 float4 each (68 float4 = 272 w)
    const int cl  = t >> 2;                   // 0..63
    const int wq0 = t & 3;
    const floatx4* __restrict__ src = (const floatx4*)(
        feat + (size_t)b * CH * NPIX + (size_t)(c0 + cl) * NPIX + (size_t)h * FW);
    #pragma unroll
    for (int k = 0; k < 17; ++k) {
        const int fidx = wq0 + 4 * k;         // 0..67
        const floatx4 v = __builtin_nontemporal_load(src + fidx);
        const int w = fidx * 4;
        tile[w + 0][cl] = f2bf(v.x);
        tile[w + 1][cl] = f2bf(v.y);
        tile[w + 2][cl] = f2bf(v.z);
        tile[w + 3][cl] = f2bf(v.w);
    }
    __syncthreads();

    // Store: per w, 64 bf16 = 32 dwords = 128 B aligned chunk (full L2 line)
    const int cd = t & 31;                    // c-pair
    const int wl = t >> 5;                    // 0..7
    unsigned* __restrict__ dstu = (unsigned*)featT;
    const size_t pixbase = (size_t)bh * FW;
    #pragma unroll
    for (int k = 0; k < 34; ++k) {
        const int w = wl + 8 * k;             // 272 = 8*34
        const unsigned p = *(const unsigned*)&tile[w][2 * cd];
        dstu[(pixbase + w) * (CH / 2) + (c0 >> 1) + cd] = p;
    }

    // ---- Fused ROI sort (block (0,0) only; uniform per-block branch) ----
    if (bh != 0 || c0 != 0) return;
    if (N > MAXN) {                           // identity fallback
        for (int i = t; i < N; i += 256) perm[i] = i;
        return;
    }
    if (t < 256) s_cnt[t] = 0;
    __syncthreads();
    for (int i = t; i < N; i += 256) {
        const float rb = rois[i * 5 + 0];
        const float y1 = rois[i * 5 + 2] * 0.25f;         // feature coords
        int yk = (int)(y1 * (128.0f / 200.0f));
        yk = min(127, max(0, yk));
        const int key = (((int)rb) & 1) * 128 + yk;
        s_key[i] = (unsigned short)key;
        atomicAdd(&s_cnt[key], 1);
    }
    __syncthreads();
    if (t < 64) {                             // wave 0: scan 256 bins, 4/lane
        const int h0 = s_cnt[t * 4], h1 = s_cnt[t * 4 + 1];
        const int h2 = s_cnt[t * 4 + 2], h3 = s_cnt[t * 4 + 3];
        const int sum = h0 + h1 + h2 + h3;
        int inc = sum;
        #pragma unroll
        for (int off = 1; off < 64; off <<= 1) {
            const int v = __shfl_up(inc, off, 64);
            if (t >= off) inc += v;
        }
        const int base = inc - sum;           // exclusive prefix
        s_base[t * 4]     = base;
        s_base[t * 4 + 1] = base + h0;
        s_base[t * 4 + 2] = base + h0 + h1;
        s_base[t * 4 + 3] = base + h0 + h1 + h2;
    }
    __syncthreads();
    if (t < 256) s_cnt[t] = 0;                // reuse as running offsets
    __syncthreads();
    for (int i = t; i < N; i += 256) {
        const int k = s_key[i];
        const int p = s_base[k] + atomicAdd(&s_cnt[k], 1);   // sorted position
        const int q = N >> 3, r = N & 7;      // bijective chunked XCD transform
        int xcd, j;
        if (p < r * (q + 1)) { xcd = p / (q + 1); j = p - xcd * (q + 1); }
        else { const int pp = p - r * (q + 1); xcd = r + pp / q; j = pp - (xcd - r) * q; }
        perm[8 * j + xcd] = i;
    }
}

// ---------- Pass 2: ROIAlign on channels-last bf16 featT ----------
// unroll 1 is deliberate: unroll 2 doubles live uint4 load destinations,
// crosses a VGPR threshold at 512 threads/block and halves occupancy
// (measured +18 us regression, Round 5). TLP > ILP for this gather loop.
__global__ __launch_bounds__(512) void roialign_cl_kernel(
    const unsigned short* __restrict__ featT,
    const float* __restrict__ rois,
    const int* __restrict__ perm,
    float* __restrict__ out, int N) {
    __shared__ int   s_yl[SY], s_yh[SY];          // offsets in DWORDS
    __shared__ float s_ly[SY], s_hy[SY];          // 0.5*weight, validity folded
    __shared__ int   s_xl[SX], s_xh[SX];
    __shared__ float s_lx[SX], s_hx[SX];
    __shared__ __align__(16) unsigned short s_out16[BINS * CH]; // 25088 B, [bin][c]

    const int n   = perm[blockIdx.x];             // XCD-locality permutation
    const int tid = threadIdx.x;
    const float* __restrict__ roi = rois + (size_t)n * 5;

    if (tid < SY + SX) {
        const bool isy = (tid < SY);
        const int  idx = isy ? tid : tid - SY;
        const int  lim = isy ? FH : FW;
        const float start = (isy ? roi[2] : roi[1]) * 0.25f;
        const float end_  = (isy ? roi[4] : roi[3]) * 0.25f;
        const float len   = fmaxf(end_ - start, 1.0f);
        const float binsz = len * (isy ? (1.0f / PH) : (1.0f / PW));
        const float s = start + ((float)idx + 0.5f) * (1.0f / SR) * binsz;
        const float valid = (s > -1.0f && s < (float)lim) ? 0.5f : 0.0f; // fold 1/SR avg
        const float cc = fminf(fmaxf(s, 0.0f), (float)(lim - 1));
        const int   lo = (int)floorf(cc);
        const int   hi = min(lo + 1, lim - 1);
        const float l  = (cc - (float)lo) * valid;
        const float hw = (1.0f - (cc - (float)lo)) * valid;
        const int   rowstride = FW * (CH / 2);     // dwords per y
        if (isy) { s_yl[idx] = lo * rowstride; s_yh[idx] = hi * rowstride;
                   s_ly[idx] = l; s_hy[idx] = hw; }
        else     { s_xl[idx] = lo * (CH / 2);  s_xh[idx] = hi * (CH / 2);
                   s_lx[idx] = l; s_hx[idx] = hw; }
    }
    __syncthreads();

    const int b  = (int)roi[0];
    const int c8 = tid & 31;              // channel octet: channels 8*c8 .. 8*c8+7
    const int g  = tid >> 5;              // 16 bin groups
    const unsigned* __restrict__ fbu =
        (const unsigned*)featT + (size_t)b * (FH * FW * (CH / 2)) + c8 * 4;

    const int bstart = g * 3;
    const int bend   = (g == 15) ? BINS : bstart + 3;  // groups: 15x3 + 1x4

    #pragma unroll 1
    for (int bin = bstart; bin < bend; ++bin) {
        const int ph = bin / 7;
        const int pw = bin - ph * 7;
        const int sy = ph * SR, sx = pw * SR;
        float a0 = 0.f, a1 = 0.f, a2 = 0.f, a3 = 0.f;
        float a4 = 0.f, a5 = 0.f, a6 = 0.f, a7 = 0.f;
        #pragma unroll
        for (int i = 0; i < SR; ++i) {
            const int   yo0 = s_yl[sy + i], yo1 = s_yh[sy + i];
            const float wy1 = s_ly[sy + i], wy0 = s_hy[sy + i];
            #pragma unroll
            for (int j = 0; j < SR; ++j) {
                const int   xo0 = s_xl[sx + j], xo1 = s_xh[sx + j];
                const float wx1 = s_lx[sx + j], wx0 = s_hx[sx + j];
                const uint4 u00 = *(const uint4*)(fbu + yo0 + xo0);
                const uint4 u01 = *(const uint4*)(fbu + yo0 + xo1);
                const uint4 u10 = *(const uint4*)(fbu + yo1 + xo0);
                const uint4 u11 = *(const uint4*)(fbu + yo1 + xo1);
                const float w00 = wy0 * wx0, w01 = wy0 * wx1;
                const float w10 = wy1 * wx0, w11 = wy1 * wx1;
                a0 += w00 * bflo(u00.x) + w01 * bflo(u01.x) + w10 * bflo(u10.x) + w11 * bflo(u11.x);
                a1 += w00 * bfhi(u00.x) + w01 * bfhi(u01.x) + w10 * bfhi(u10.x) + w11 * bfhi(u11.x);
                a2 += w00 * bflo(u00.y) + w01 * bflo(u01.y) + w10 * bflo(u10.y) + w11 * bflo(u11.y);
                a3 += w00 * bfhi(u00.y) + w01 * bfhi(u01.y) + w10 * bfhi(u10.y) + w11 * bfhi(u11.y);
                a4 += w00 * bflo(u00.z) + w01 * bflo(u01.z) + w10 * bflo(u10.z) + w11 * bflo(u11.z);
                a5 += w00 * bfhi(u00.z) + w01 * bfhi(u01.z) + w10 * bfhi(u10.z) + w11 * bfhi(u11.z);
                a6 += w00 * bflo(u00.w) + w01 * bflo(u01.w) + w10 * bflo(u10.w) + w11 * bflo(u11.w);
                a7 += w00 * bfhi(u00.w) + w01 * bfhi(u01.w) + w10 * bfhi(u10.w) + w11 * bfhi(u11.w);
            }
        }
        uint4 p;
        p.x = (unsigned)f2bf(a0) | ((unsigned)f2bf(a1) << 16);
        p.y = (unsigned)f2bf(a2) | ((unsigned)f2bf(a3) << 16);
        p.z = (unsigned)f2bf(a4) | ((unsigned)f2bf(a5) << 16);
        p.w = (unsigned)f2bf(a6) | ((unsigned)f2bf(a7) << 16);
        const int col = (c8 ^ (bin & 31)) * 8;     // per-bin octet swizzle
        *(uint4*)&s_out16[bin * CH + col] = p;
    }
    __syncthreads();

    // Coalesced fp32 non-temporal flush of this ROI's [C, 7, 7] tile
    float* __restrict__ outn = out + (size_t)n * (CH * BINS);
    #pragma unroll 1
    for (int k = 0; k < 24; ++k) {                 // 24*512 = 12288
        const int e   = k * 512 + tid;             // = c*49 + bin
        const int c   = e / 49;
        const int bin = e - c * 49;
        const int oct = (c >> 3) ^ (bin & 31);     // undo swizzle
        __builtin_nontemporal_store(
            bflo((unsigned)s_out16[bin * CH + oct * 8 + (c & 7)]), &outn[e]);
    }
    if (tid < 256) {                               // tail: 12288..12543
        const int e   = 12288 + tid;
        const int c   = e / 49;
        const int bin = e - c * 49;
        const int oct = (c >> 3) ^ (bin & 31);
        __builtin_nontemporal_store(
            bflo((unsigned)s_out16[bin * CH + oct * 8 + (c & 7)]), &outn[e]);
    }
}

// ---------- Fallback (fp32, no workspace) ----------
__global__ __launch_bounds__(256) void roialign_kernel(
    const float* __restrict__ feat,
    const float* __restrict__ rois,
    float* __restrict__ out, int N) {
    __shared__ int   s_yl[SY], s_yh[SY];
    __shared__ float s_ly[SY], s_hy[SY];
    __shared__ int   s_xl[SX], s_xh[SX];
    __shared__ float s_lx[SX], s_hx[SX];
    __shared__ float s_out[CH * BINS];

    const int n   = blockIdx.x;
    const int tid = threadIdx.x;
    const float* __restrict__ roi = rois + (size_t)n * 5;

    if (tid < SY + SX) {
        const bool isy = (tid < SY);
        const int  idx = isy ? tid : tid - SY;
        const int  lim = isy ? FH : FW;
        const float start = (isy ? roi[2] : roi[1]) * 0.25f;
        const float end_  = (isy ? roi[4] : roi[3]) * 0.25f;
        const float len   = fmaxf(end_ - start, 1.0f);
        const float binsz = len * (isy ? (1.0f / PH) : (1.0f / PW));
        const float s = start + ((float)idx + 0.5f) * (1.0f / SR) * binsz;
        const float valid = (s > -1.0f && s < (float)lim) ? 1.0f : 0.0f;
        const float cc = fminf(fmaxf(s, 0.0f), (float)(lim - 1));
        const int   lo = (int)floorf(cc);
        const int   hi = min(lo + 1, lim - 1);
        const float l  = (cc - (float)lo) * valid;
        const float hw = (1.0f - (cc - (float)lo)) * valid;
        if (isy) { s_yl[idx] = lo; s_yh[idx] = hi; s_ly[idx] = l; s_hy[idx] = hw; }
        else     { s_xl[idx] = lo; s_xh[idx] = hi; s_lx[idx] = l; s_hx[idx] = hw; }
    }
    __syncthreads();

    const int b = (int)roi[0];
    const int c = tid;
    const float* __restrict__ fp = feat + ((size_t)b * CH + c) * (size_t)NPIX;

    #pragma unroll 1
    for (int ph = 0; ph < PH; ++ph) {
        const int sy0 = ph * SR;
        const float* r00 = fp + s_yl[sy0] * FW;
        const float* r01 = fp + s_yh[sy0] * FW;
        const float* r10 = fp + s_yl[sy0 + 1] * FW;
        const float* r11 = fp + s_yh[sy0 + 1] * FW;
        const float ly0 = s_ly[sy0],     hy0 = s_hy[sy0];
        const float ly1 = s_ly[sy0 + 1], hy1 = s_hy[sy0 + 1];
        for (int pw = 0; pw < PW; ++pw) {
            const int sx0 = pw * SR;
            float acc = 0.0f;
            #pragma unroll
            for (int j = 0; j < SR; ++j) {
                const int   xl = s_xl[sx0 + j], xh = s_xh[sx0 + j];
                const float lx = s_lx[sx0 + j], hx = s_hx[sx0 + j];
                acc += hy0 * (hx * r00[xl] + lx * r00[xh])
                     + ly0 * (hx * r01[xl] + lx * r01[xh]);
                acc += hy1 * (hx * r10[xl] + lx * r10[xh])
                     + ly1 * (hx * r11[xl] + lx * r11[xh]);
            }
            s_out[c * BINS + ph * PW + pw] = acc * 0.25f;
        }
    }
    __syncthreads();

    float* __restrict__ outn = out + (size_t)n * (CH * BINS);
    #pragma unroll
    for (int k = 0; k < BINS; ++k) {
        const int idx = k * 256 + tid;
        outn[idx] = s_out[idx];
    }
}

extern "C" void kernel_launch(void* const* d_in, const int* in_sizes, int n_in,
                              void* d_out, int out_size, void* d_ws, size_t ws_size,
                              hipStream_t stream) {
    const float* feat = (const float*)d_in[0];
    const float* rois = (const float*)d_in[1];
    float* out = (float*)d_out;
    const int N = in_sizes[1] / 5;
    const int B = in_sizes[0] / (CH * NPIX);
    const size_t featT_bytes = (size_t)B * CH * NPIX * sizeof(unsigned short);
    const size_t need = featT_bytes + (size_t)N * sizeof(int);

    if (ws_size >= need) {
        unsigned short* featT = (unsigned short*)d_ws;
        int* perm = (int*)((char*)d_ws + featT_bytes);
        dim3 tgrid(B * FH, CH / 64);
        transpose_kernel<<<tgrid, 256, 0, stream>>>(feat, featT, rois, perm, N);
        roialign_cl_kernel<<<N, 512, 0, stream>>>(featT, rois, perm, out, N);
    } else {
        roialign_kernel<<<N, 256, 0, stream>>>(feat, rois, out, N);
    }
}

// Round 8
// 209.702 us; speedup vs baseline: 1.1143x; 1.0072x over previous
//
#include <hip/hip_runtime.h>

#define PH 7
#define PW 7
#define SR 2
#define SY (PH * SR)   // 14
#define SX (PW * SR)   // 14
#define CH 256
#define FH 200
#define FW 272
#define BINS (PH * PW) // 49
#define NPIX (FH * FW) // 54400
#define MAXN 1024

typedef float  floatx4 __attribute__((ext_vector_type(4)));

__device__ __forceinline__ unsigned short f2bf(float f) {
    unsigned x = __float_as_uint(f);
    return (unsigned short)((x + 0x7fffu + ((x >> 16) & 1u)) >> 16);
}
__device__ __forceinline__ float bflo(unsigned u) { return __uint_as_float(u << 16); }
__device__ __forceinline__ float bfhi(unsigned u) { return __uint_as_float(u & 0xffff0000u); }

// ---------- Pass 1 (+0): feat [B,C,H,W] fp32 -> featT [B,H,W,C] bf16,
// with the ROI sort fused into block (0,0) (saves one dispatch; the sort's
// ~1.5 us hides under the other 1599 BW-bound blocks). Sorted position p maps
// bijectively to blockIdx bid = 8*j + xcd so same-XCD roialign blocks process
// ROIs with adjacent y (L2 overlap).
__global__ __launch_bounds__(256) void transpose_kernel(
    const float* __restrict__ feat, unsigned short* __restrict__ featT,
    const float* __restrict__ rois, int* __restrict__ perm, int N) {
    __shared__ __align__(16) unsigned short tile[FW][66];   // 35904 B
    __shared__ unsigned short s_key[MAXN];                  // sort scratch (blk 0)
    __shared__ int s_base[256];
    __shared__ int s_cnt[256];
    const int t  = threadIdx.x;
    const int bh = blockIdx.x;                // b*FH + h
    const int c0 = blockIdx.y * 64;
    const int b  = bh / FH;
    const int h  = bh % FH;

    // Load: 4 lanes per channel row, 17 float4 each (68 float4 = 272 w)
    const int cl  = t >> 2;                   // 0..63
    const int wq0 = t & 3;
    const floatx4* __restrict__ src = (const floatx4*)(
        feat + (size_t)b * CH * NPIX + (size_t)(c0 + cl) * NPIX + (size_t)h * FW);
    #pragma unroll
    for (int k = 0; k < 17; ++k) {
        const int fidx = wq0 + 4 * k;         // 0..67
        const floatx4 v = __builtin_nontemporal_load(src + fidx);
        const int w = fidx * 4;
        tile[w + 0][cl] = f2bf(v.x);
        tile[w + 1][cl] = f2bf(v.y);
        tile[w + 2][cl] = f2bf(v.z);
        tile[w + 3][cl] = f2bf(v.w);
    }
    __syncthreads();

    // Store: per w, 64 bf16 = 32 dwords = 128 B aligned chunk (full L2 line)
    const int cd = t & 31;                    // c-pair
    const int wl = t >> 5;                    // 0..7
    unsigned* __restrict__ dstu = (unsigned*)featT;
    const size_t pixbase = (size_t)bh * FW;
    #pragma unroll
    for (int k = 0; k < 34; ++k) {
        const int w = wl + 8 * k;             // 272 = 8*34
        const unsigned p = *(const unsigned*)&tile[w][2 * cd];
        dstu[(pixbase + w) * (CH / 2) + (c0 >> 1) + cd] = p;
    }

    // ---- Fused ROI sort (block (0,0) only; uniform per-block branch) ----
    if (bh != 0 || c0 != 0) return;
    if (N > MAXN) {                           // identity fallback
        for (int i = t; i < N; i += 256) perm[i] = i;
        return;
    }
    if (t < 256) s_cnt[t] = 0;
    __syncthreads();
    for (int i = t; i < N; i += 256) {
        const float rb = rois[i * 5 + 0];
        const float y1 = rois[i * 5 + 2] * 0.25f;         // feature coords
        int yk = (int)(y1 * (128.0f / 200.0f));
        yk = min(127, max(0, yk));
        const int key = (((int)rb) & 1) * 128 + yk;
        s_key[i] = (unsigned short)key;
        atomicAdd(&s_cnt[key], 1);
    }
    __syncthreads();
    if (t < 64) {                             // wave 0: scan 256 bins, 4/lane
        const int h0 = s_cnt[t * 4], h1 = s_cnt[t * 4 + 1];
        const int h2 = s_cnt[t * 4 + 2], h3 = s_cnt[t * 4 + 3];
        const int sum = h0 + h1 + h2 + h3;
        int inc = sum;
        #pragma unroll
        for (int off = 1; off < 64; off <<= 1) {
            const int v = __shfl_up(inc, off, 64);
            if (t >= off) inc += v;
        }
        const int base = inc - sum;           // exclusive prefix
        s_base[t * 4]     = base;
        s_base[t * 4 + 1] = base + h0;
        s_base[t * 4 + 2] = base + h0 + h1;
        s_base[t * 4 + 3] = base + h0 + h1 + h2;
    }
    __syncthreads();
    if (t < 256) s_cnt[t] = 0;                // reuse as running offsets
    __syncthreads();
    for (int i = t; i < N; i += 256) {
        const int k = s_key[i];
        const int p = s_base[k] + atomicAdd(&s_cnt[k], 1);   // sorted position
        const int q = N >> 3, r = N & 7;      // bijective chunked XCD transform
        int xcd, j;
        if (p < r * (q + 1)) { xcd = p / (q + 1); j = p - xcd * (q + 1); }
        else { const int pp = p - r * (q + 1); xcd = r + pp / q; j = pp - (xcd - r) * q; }
        perm[8 * j + xcd] = i;
    }
}

// ---------- Pass 2: ROIAlign on channels-last bf16 featT ----------
// unroll 1 is deliberate: unroll 2 doubles live uint4 load destinations,
// crosses a VGPR threshold at 512 threads/block and halves occupancy
// (measured +18 us regression, Round 5). TLP > ILP for this gather loop.
// Bin order is STRIDED (bin = g, g+16, ...): at any phase all 16 groups work
// the spatially-contiguous bins [16k,16k+16) (~2.3 bin-rows), shrinking the
// block's live texel working set ~3x so duplicate corner reads hit L1/L2.
__global__ __launch_bounds__(512) void roialign_cl_kernel(
    const unsigned short* __restrict__ featT,
    const float* __restrict__ rois,
    const int* __restrict__ perm,
    float* __restrict__ out, int N) {
    __shared__ int   s_yl[SY], s_yh[SY];          // offsets in DWORDS
    __shared__ float s_ly[SY], s_hy[SY];          // 0.5*weight, validity folded
    __shared__ int   s_xl[SX], s_xh[SX];
    __shared__ float s_lx[SX], s_hx[SX];
    __shared__ __align__(16) unsigned short s_out16[BINS * CH]; // 25088 B, [bin][c]

    const int n   = perm[blockIdx.x];             // XCD-locality permutation
    const int tid = threadIdx.x;
    const float* __restrict__ roi = rois + (size_t)n * 5;

    if (tid < SY + SX) {
        const bool isy = (tid < SY);
        const int  idx = isy ? tid : tid - SY;
        const int  lim = isy ? FH : FW;
        const float start = (isy ? roi[2] : roi[1]) * 0.25f;
        const float end_  = (isy ? roi[4] : roi[3]) * 0.25f;
        const float len   = fmaxf(end_ - start, 1.0f);
        const float binsz = len * (isy ? (1.0f / PH) : (1.0f / PW));
        const float s = start + ((float)idx + 0.5f) * (1.0f / SR) * binsz;
        const float valid = (s > -1.0f && s < (float)lim) ? 0.5f : 0.0f; // fold 1/SR avg
        const float cc = fminf(fmaxf(s, 0.0f), (float)(lim - 1));
        const int   lo = (int)floorf(cc);
        const int   hi = min(lo + 1, lim - 1);
        const float l  = (cc - (float)lo) * valid;
        const float hw = (1.0f - (cc - (float)lo)) * valid;
        const int   rowstride = FW * (CH / 2);     // dwords per y
        if (isy) { s_yl[idx] = lo * rowstride; s_yh[idx] = hi * rowstride;
                   s_ly[idx] = l; s_hy[idx] = hw; }
        else     { s_xl[idx] = lo * (CH / 2);  s_xh[idx] = hi * (CH / 2);
                   s_lx[idx] = l; s_hx[idx] = hw; }
    }
    __syncthreads();

    const int b  = (int)roi[0];
    const int c8 = tid & 31;              // channel octet: channels 8*c8 .. 8*c8+7
    const int g  = tid >> 5;              // 16 bin groups
    const unsigned* __restrict__ fbu =
        (const unsigned*)featT + (size_t)b * (FH * FW * (CH / 2)) + c8 * 4;

    // strided: group g handles bins {g, g+16, g+32(, g+48)} — g=0 gets 4, rest 3
    #pragma unroll 1
    for (int bin = g; bin < BINS; bin += 16) {
        const int ph = bin / 7;
        const int pw = bin - ph * 7;
        const int sy = ph * SR, sx = pw * SR;
        float a0 = 0.f, a1 = 0.f, a2 = 0.f, a3 = 0.f;
        float a4 = 0.f, a5 = 0.f, a6 = 0.f, a7 = 0.f;
        #pragma unroll
        for (int i = 0; i < SR; ++i) {
            const int   yo0 = s_yl[sy + i], yo1 = s_yh[sy + i];
            const float wy1 = s_ly[sy + i], wy0 = s_hy[sy + i];
            #pragma unroll
            for (int j = 0; j < SR; ++j) {
                const int   xo0 = s_xl[sx + j], xo1 = s_xh[sx + j];
                const float wx1 = s_lx[sx + j], wx0 = s_hx[sx + j];
                const uint4 u00 = *(const uint4*)(fbu + yo0 + xo0);
                const uint4 u01 = *(const uint4*)(fbu + yo0 + xo1);
                const uint4 u10 = *(const uint4*)(fbu + yo1 + xo0);
                const uint4 u11 = *(const uint4*)(fbu + yo1 + xo1);
                const float w00 = wy0 * wx0, w01 = wy0 * wx1;
                const float w10 = wy1 * wx0, w11 = wy1 * wx1;
                a0 += w00 * bflo(u00.x) + w01 * bflo(u01.x) + w10 * bflo(u10.x) + w11 * bflo(u11.x);
                a1 += w00 * bfhi(u00.x) + w01 * bfhi(u01.x) + w10 * bfhi(u10.x) + w11 * bfhi(u11.x);
                a2 += w00 * bflo(u00.y) + w01 * bflo(u01.y) + w10 * bflo(u10.y) + w11 * bflo(u11.y);
                a3 += w00 * bfhi(u00.y) + w01 * bfhi(u01.y) + w10 * bfhi(u10.y) + w11 * bfhi(u11.y);
                a4 += w00 * bflo(u00.z) + w01 * bflo(u01.z) + w10 * bflo(u10.z) + w11 * bflo(u11.z);
                a5 += w00 * bfhi(u00.z) + w01 * bfhi(u01.z) + w10 * bfhi(u10.z) + w11 * bfhi(u11.z);
                a6 += w00 * bflo(u00.w) + w01 * bflo(u01.w) + w10 * bflo(u10.w) + w11 * bflo(u11.w);
                a7 += w00 * bfhi(u00.w) + w01 * bfhi(u01.w) + w10 * bfhi(u10.w) + w11 * bfhi(u11.w);
            }
        }
        uint4 p;
        p.x = (unsigned)f2bf(a0) | ((unsigned)f2bf(a1) << 16);
        p.y = (unsigned)f2bf(a2) | ((unsigned)f2bf(a3) << 16);
        p.z = (unsigned)f2bf(a4) | ((unsigned)f2bf(a5) << 16);
        p.w = (unsigned)f2bf(a6) | ((unsigned)f2bf(a7) << 16);
        const int col = (c8 ^ (bin & 31)) * 8;     // per-bin octet swizzle
        *(uint4*)&s_out16[bin * CH + col] = p;
    }
    __syncthreads();

    // Coalesced fp32 non-temporal flush of this ROI's [C, 7, 7] tile
    float* __restrict__ outn = out + (size_t)n * (CH * BINS);
    #pragma unroll 1
    for (int k = 0; k < 24; ++k) {                 // 24*512 = 12288
        const int e   = k * 512 + tid;             // = c*49 + bin
        const int c   = e / 49;
        const int bin = e - c * 49;
        const int oct = (c >> 3) ^ (bin & 31);     // undo swizzle
        __builtin_nontemporal_store(
            bflo((unsigned)s_out16[bin * CH + oct * 8 + (c & 7)]), &outn[e]);
    }
    if (tid < 256) {                               // tail: 12288..12543
        const int e   = 12288 + tid;
        const int c   = e / 49;
        const int bin = e - c * 49;
        const int oct = (c >> 3) ^ (bin & 31);
        __builtin_nontemporal_store(
            bflo((unsigned)s_out16[bin * CH + oct * 8 + (c & 7)]), &outn[e]);
    }
}

// ---------- Fallback (fp32, no workspace) ----------
__global__ __launch_bounds__(256) void roialign_kernel(
    const float* __restrict__ feat,
    const float* __restrict__ rois,
    float* __restrict__ out, int N) {
    __shared__ int   s_yl[SY], s_yh[SY];
    __shared__ float s_ly[SY], s_hy[SY];
    __shared__ int   s_xl[SX], s_xh[SX];
    __shared__ float s_lx[SX], s_hx[SX];
    __shared__ float s_out[CH * BINS];

    const int n   = blockIdx.x;
    const int tid = threadIdx.x;
    const float* __restrict__ roi = rois + (size_t)n * 5;

    if (tid < SY + SX) {
        const bool isy = (tid < SY);
        const int  idx = isy ? tid : tid - SY;
        const int  lim = isy ? FH : FW;
        const float start = (isy ? roi[2] : roi[1]) * 0.25f;
        const float end_  = (isy ? roi[4] : roi[3]) * 0.25f;
        const float len   = fmaxf(end_ - start, 1.0f);
        const float binsz = len * (isy ? (1.0f / PH) : (1.0f / PW));
        const float s = start + ((float)idx + 0.5f) * (1.0f / SR) * binsz;
        const float valid = (s > -1.0f && s < (float)lim) ? 1.0f : 0.0f;
        const float cc = fminf(fmaxf(s, 0.0f), (float)(lim - 1));
        const int   lo = (int)floorf(cc);
        const int   hi = min(lo + 1, lim - 1);
        const float l  = (cc - (float)lo) * valid;
        const float hw = (1.0f - (cc - (float)lo)) * valid;
        if (isy) { s_yl[idx] = lo; s_yh[idx] = hi; s_ly[idx] = l; s_hy[idx] = hw; }
        else     { s_xl[idx] = lo; s_xh[idx] = hi; s_lx[idx] = l; s_hx[idx] = hw; }
    }
    __syncthreads();

    const int b = (int)roi[0];
    const int c = tid;
    const float* __restrict__ fp = feat + ((size_t)b * CH + c) * (size_t)NPIX;

    #pragma unroll 1
    for (int ph = 0; ph < PH; ++ph) {
        const int sy0 = ph * SR;
        const float* r00 = fp + s_yl[sy0] * FW;
        const float* r01 = fp + s_yh[sy0] * FW;
        const float* r10 = fp + s_yl[sy0 + 1] * FW;
        const float* r11 = fp + s_yh[sy0 + 1] * FW;
        const float ly0 = s_ly[sy0],     hy0 = s_hy[sy0];
        const float ly1 = s_ly[sy0 + 1], hy1 = s_hy[sy0 + 1];
        for (int pw = 0; pw < PW; ++pw) {
            const int sx0 = pw * SR;
            float acc = 0.0f;
            #pragma unroll
            for (int j = 0; j < SR; ++j) {
                const int   xl = s_xl[sx0 + j], xh = s_xh[sx0 + j];
                const float lx = s_lx[sx0 + j], hx = s_hx[sx0 + j];
                acc += hy0 * (hx * r00[xl] + lx * r00[xh])
                     + ly0 * (hx * r01[xl] + lx * r01[xh]);
                acc += hy1 * (hx * r10[xl] + lx * r10[xh])
                     + ly1 * (hx * r11[xl] + lx * r11[xh]);
            }
            s_out[c * BINS + ph * PW + pw] = acc * 0.25f;
        }
    }
    __syncthreads();

    float* __restrict__ outn = out + (size_t)n * (CH * BINS);
    #pragma unroll
    for (int k = 0; k < BINS; ++k) {
        const int idx = k * 256 + tid;
        outn[idx] = s_out[idx];
    }
}

extern "C" void kernel_launch(void* const* d_in, const int* in_sizes, int n_in,
                              void* d_out, int out_size, void* d_ws, size_t ws_size,
                              hipStream_t stream) {
    const float* feat = (const float*)d_in[0];
    const float* rois = (const float*)d_in[1];
    float* out = (float*)d_out;
    const int N = in_sizes[1] / 5;
    const int B = in_sizes[0] / (CH * NPIX);
    const size_t featT_bytes = (size_t)B * CH * NPIX * sizeof(unsigned short);
    const size_t need = featT_bytes + (size_t)N * sizeof(int);

    if (ws_size >= need) {
        unsigned short* featT = (unsigned short*)d_ws;
        int* perm = (int*)((char*)d_ws + featT_bytes);
        dim3 tgrid(B * FH, CH / 64);
        transpose_kernel<<<tgrid, 256, 0, stream>>>(feat, featT, rois, perm, N);
        roialign_cl_kernel<<<N, 512, 0, stream>>>(featT, rois, perm, out, N);
    } else {
        roialign_kernel<<<N, 256, 0, stream>>>(feat, rois, out, N);
    }
}